// Round 7
// baseline (4465.986 us; speedup 1.0000x reference)
//
#include <hip/hip_runtime.h>
#include <stdint.h>

#define T_STEPS 64
#define BATCH   512
#define OBS_DIM 256
#define ACT_DIM 32
#define HID     1024
#define FEAT    512
#define GDIM    3072
#define KIH     288
#define KF      544          // folded GRU K: 512 (Z2 obs) + 32 (action)
#define NBLK    256
#define GMEMB   32           // blocks per group
#define LOG2PI  1.8378770664093453f
#define HWREG_XCC_ID 14356   // hwreg(id=20 XCC_ID, offset=0, size=8)

typedef __attribute__((ext_vector_type(8))) short  short8;   // 8 bf16
typedef __attribute__((ext_vector_type(4))) float  floatx4;  // MFMA C/D frag
typedef __attribute__((ext_vector_type(4))) unsigned int uintx4;
typedef unsigned long long ull;

__device__ __forceinline__ float bf2f(unsigned int u) {
    return __uint_as_float(u << 16);
}
__device__ __forceinline__ unsigned int f2bf(float f) {
    unsigned int u = __float_as_uint(f);
    return (u + 0x7FFFu + ((u >> 16) & 1u)) >> 16;  // RNE
}
__device__ __forceinline__ float elu1(float x)  { return x > 0.f ? x : expm1f(x); }
__device__ __forceinline__ float sigm(float x)  { return 1.f / (1.f + expf(-x)); }

// Coherent accessors — device scope.
__device__ __forceinline__ unsigned int dev_ld(const unsigned int* p) {
    return __hip_atomic_load(p, __ATOMIC_RELAXED, __HIP_MEMORY_SCOPE_AGENT);
}
__device__ __forceinline__ ull dev_ld64(const ull* p) {
    return __hip_atomic_load(p, __ATOMIC_RELAXED, __HIP_MEMORY_SCOPE_AGENT);
}
__device__ __forceinline__ void dev_st(unsigned int* p, unsigned int v) {
    __hip_atomic_store(p, v, __ATOMIC_RELAXED, __HIP_MEMORY_SCOPE_AGENT);
}
__device__ __forceinline__ float dev_ldf(const float* p) {
    return __uint_as_float(dev_ld((const unsigned int*)p));
}

template<bool COH>
__device__ __forceinline__ unsigned int a_ld(const unsigned int* p) {
    return COH ? dev_ld(p) : *p;
}
template<bool COH>
__device__ __forceinline__ ull a_ld64(const ull* p) {
    return COH ? dev_ld64(p) : *p;
}
template<bool COH>
__device__ __forceinline__ void a_st(unsigned int* p, unsigned int v) {
    if (COH) dev_st(p, v); else *p = v;
}

struct ParamsReal {
    const float* obs; const float* action; const float* reward;
    const float* b_ih; const float* b_hh;
    const float* b1o; const float* b1r; const float* b2o; const float* b2r;
    const unsigned short* Ws1; const unsigned short* Wih;
    const unsigned short* W1o; const unsigned short* W1r;
    const unsigned short* W2o; const unsigned short* w2r;
    const unsigned short* Wf;  const float* bf_fold;
    const float* bias_s1;
    // Single-buffered intermediates (safe: each is written in one stage and
    // consumed before the next write, with >=2 group rendezvous in between).
    unsigned short* Z1; unsigned short* Z2; unsigned short* Xbuf1;
    unsigned short* hbf; unsigned short* GHb; float* h[2];
    float* accum; float* out;
    int* bar;
};
#define P ParamsReal

// ---------------------------------------------------------------------------
// Raw block barriers (no compiler vmcnt(0) drain).
// ---------------------------------------------------------------------------
__device__ __forceinline__ void bar_fast() {
    asm volatile("" ::: "memory");
    __builtin_amdgcn_s_barrier();
    asm volatile("" ::: "memory");
}
__device__ __forceinline__ void bar_lds() {
    asm volatile("s_waitcnt lgkmcnt(0)" ::: "memory");
    __builtin_amdgcn_s_barrier();
    asm volatile("" ::: "memory");
}

// ---------------------------------------------------------------------------
// Atomic-counter barrier — entry/exit rendezvous only.
// ---------------------------------------------------------------------------
__device__ __forceinline__ void gbar(int* cnt, int* gen, int& epoch, int members) {
    __syncthreads();
    if (threadIdx.x == 0) {
        __builtin_amdgcn_fence(__ATOMIC_RELEASE, "workgroup");
        epoch++;
        int prev = __hip_atomic_fetch_add(cnt, 1, __ATOMIC_RELAXED,
                                          __HIP_MEMORY_SCOPE_AGENT);
        if (prev == members * epoch - 1) {
            __hip_atomic_store(gen, epoch, __ATOMIC_RELAXED,
                               __HIP_MEMORY_SCOPE_AGENT);
        } else {
            while (__hip_atomic_load(gen, __ATOMIC_RELAXED,
                                     __HIP_MEMORY_SCOPE_AGENT) < epoch)
                __builtin_amdgcn_s_sleep(2);
        }
        __builtin_amdgcn_fence(__ATOMIC_ACQUIRE, "workgroup");
    }
    __syncthreads();
}

// ---------------------------------------------------------------------------
// Flag-array group barrier, split into arrive (drain + post) and wait (poll).
// arrive's __syncthreads drains vmcnt -> data stores visible before the flag.
// ---------------------------------------------------------------------------
__device__ __forceinline__ void arrive_flags(int* fbase, int m, int epoch) {
    __syncthreads();
    if (threadIdx.x == 0) {
        __builtin_amdgcn_fence(__ATOMIC_RELEASE, "workgroup");
        dev_st((unsigned int*)(fbase + m * 16), (unsigned int)epoch);
    }
}
__device__ __forceinline__ void wait_flags(int* fbase, int epoch) {
    if (threadIdx.x < 64) {
        const unsigned int* fp =
            (const unsigned int*)(fbase + (threadIdx.x & 31) * 16);
        while ((int)dev_ld(fp) < epoch) __builtin_amdgcn_s_sleep(4);
        __builtin_amdgcn_fence(__ATOMIC_ACQUIRE, "workgroup");
    }
    __syncthreads();
}
__device__ __forceinline__ void gbar_flags(int* fbase, int m, int& epoch) {
    epoch++;
    arrive_flags(fbase, m, epoch);
    wait_flags(fbase, epoch);
}

// ---------------------------------------------------------------------------
// S1: C[64 x 4096] = hbf[g] @ Ws1^T + bias. tile 64x128, K=1024. (R1 verbatim)
// ---------------------------------------------------------------------------
template<bool COH>
__device__ __forceinline__ void s1_stage(const P& p, unsigned short* lds,
                                         int g, int m,
                                         const unsigned short* hbf_r,
                                         unsigned short* Z1_w,
                                         unsigned short* GHb_w) {
    const int tid = threadIdx.x, lane = tid & 63, wv = tid >> 6;
    const int wr = wv & 1, wc = wv >> 1, fr = lane & 15, fq = lane >> 4;
    const int rowg = g * 64, col0 = m * 128;
    unsigned short* ldsA = lds;               // 64 x 136
    unsigned short* ldsB = lds + 64 * 136;    // 128 x 72

    floatx4 acc[2][4];
    floatx4 z4 = {0.f, 0.f, 0.f, 0.f};
#pragma unroll
    for (int mi = 0; mi < 2; ++mi)
#pragma unroll
        for (int n = 0; n < 4; ++n) acc[mi][n] = z4;

    const ull* Aq = (const ull*)(hbf_r + (size_t)rowg * HID);
    const unsigned short* Bg = p.Ws1 + (size_t)col0 * HID;

    ull apf[8];
#pragma unroll
    for (int j = 0; j < 8; ++j) { int f = tid + 256 * j;
        apf[j] = a_ld64<COH>(Aq + (size_t)(f >> 5) * 256 + (f & 31)); }
    uintx4 rb0[4], rb1[4];
#pragma unroll
    for (int i = 0; i < 4; ++i) { int c = tid + 256 * i;
        const unsigned short* bp = Bg + (size_t)(c >> 3) * HID + ((c & 7) << 3);
        rb0[i] = __builtin_nontemporal_load((const uintx4*)bp);
        rb1[i] = __builtin_nontemporal_load((const uintx4*)(bp + 64)); }

#define S1_MFMA(ASUB)                                                          \
    {                                                                          \
        _Pragma("unroll")                                                      \
        for (int ks = 0; ks < 2; ++ks) {                                       \
            short8 af[2], bf8[4];                                              \
            _Pragma("unroll")                                                  \
            for (int mi = 0; mi < 2; ++mi)                                     \
                af[mi] = *(const short8*)(ldsA + (wr * 32 + mi * 16 + fr) * 136 + (ASUB) + ks * 32 + fq * 8); \
            _Pragma("unroll")                                                  \
            for (int n = 0; n < 4; ++n)                                        \
                bf8[n] = *(const short8*)(ldsB + (wc * 64 + n * 16 + fr) * 72 + ks * 32 + fq * 8); \
            _Pragma("unroll")                                                  \
            for (int mi = 0; mi < 2; ++mi)                                     \
                _Pragma("unroll")                                              \
                for (int n = 0; n < 4; ++n)                                    \
                    acc[mi][n] = __builtin_amdgcn_mfma_f32_16x16x32_bf16(      \
                        af[mi], bf8[n], acc[mi][n], 0, 0, 0);                  \
        }                                                                      \
    }

    for (int it2 = 0; it2 < 8; ++it2) {
        bar_fast();
#pragma unroll
        for (int j = 0; j < 8; ++j) { int f = tid + 256 * j;
            *(ull*)(ldsA + (size_t)(f >> 5) * 136 + ((f & 31) << 2)) = apf[j]; }
#pragma unroll
        for (int i = 0; i < 4; ++i) { int c = tid + 256 * i;
            *(uintx4*)(ldsB + (c >> 3) * 72 + ((c & 7) << 3)) = rb0[i]; }
        bar_lds();
        if (it2 < 7) {
            int c2 = it2 + 1;
#pragma unroll
            for (int j = 0; j < 8; ++j) { int f = tid + 256 * j;
                apf[j] = a_ld64<COH>(Aq + (size_t)(f >> 5) * 256 + c2 * 32 + (f & 31)); }
            int k0n = (2 * it2 + 2) * 64;
#pragma unroll
            for (int i = 0; i < 4; ++i) { int c = tid + 256 * i;
                rb0[i] = __builtin_nontemporal_load((const uintx4*)
                    (Bg + (size_t)(c >> 3) * HID + k0n + ((c & 7) << 3))); }
        }
        S1_MFMA(0);
        bar_fast();
#pragma unroll
        for (int i = 0; i < 4; ++i) { int c = tid + 256 * i;
            *(uintx4*)(ldsB + (c >> 3) * 72 + ((c & 7) << 3)) = rb1[i]; }
        bar_lds();
        if (it2 < 7) {
            int k0n = (2 * it2 + 3) * 64;
#pragma unroll
            for (int i = 0; i < 4; ++i) { int c = tid + 256 * i;
                rb1[i] = __builtin_nontemporal_load((const uintx4*)
                    (Bg + (size_t)(c >> 3) * HID + k0n + ((c & 7) << 3))); }
        }
        S1_MFMA(64);
    }
#undef S1_MFMA

    const bool isZ1 = (col0 < 1024);
#pragma unroll
    for (int mi = 0; mi < 2; ++mi)
#pragma unroll
        for (int n = 0; n < 4; ++n)
#pragma unroll
            for (int j = 0; j < 4; ++j) {
                int row = rowg + wr * 32 + mi * 16 + fq * 4 + j;
                int col = col0 + wc * 64 + n * 16 + fr;
                float v = acc[mi][n][j] + p.bias_s1[col];
                unsigned int ow = f2bf(isZ1 ? elu1(v) : v);
                unsigned int pr = __shfl_xor(ow, 1, 64);
                if (!(fr & 1)) {
                    unsigned int pk = ow | (pr << 16);
                    if (isZ1)
                        a_st<COH>((unsigned int*)(Z1_w + row * HID + col), pk);
                    else
                        a_st<COH>((unsigned int*)GHb_w + (size_t)row * 1536 + ((col - 1024) >> 1), pk);
                }
            }
}

// ---------------------------------------------------------------------------
// S2: Z2 = elu(Z1 half @ W1z^T + b). K=512. (R1 verbatim)
// ---------------------------------------------------------------------------
template<bool COH>
__device__ __forceinline__ void s2_stage(const P& p, unsigned short* lds,
                                         int g, int m,
                                         const unsigned short* Z1_r,
                                         unsigned short* Z2_w) {
    const int tid = threadIdx.x, lane = tid & 63, wv = tid >> 6;
    const int wr = wv & 1, wc = wv >> 1, fr = lane & 15, fq = lane >> 4;
    const int rowg = g * 64;
    const int z = m >> 4, col0 = (m & 15) * 32;
    unsigned short* ldsA = lds;               // 64 x 136
    unsigned short* ldsB = lds + 64 * 136;    // 32 x 72

    floatx4 acc[2];
    floatx4 z4 = {0.f, 0.f, 0.f, 0.f};
    acc[0] = z4; acc[1] = z4;

    const ull* Aq = (const ull*)(Z1_r + (size_t)rowg * HID + z * FEAT);
    const unsigned short* Bg = (z ? p.W1r : p.W1o) + (size_t)col0 * FEAT;
    const float* bias = z ? p.b1r : p.b1o;

    ull apf[8];
#pragma unroll
    for (int j = 0; j < 8; ++j) { int f = tid + 256 * j;
        apf[j] = a_ld64<COH>(Aq + (size_t)(f >> 5) * 256 + (f & 31)); }
    const unsigned short* bp0 = Bg + (size_t)(tid >> 3) * FEAT + ((tid & 7) << 3);
    uintx4 rb0 = *(const uintx4*)(bp0);
    uintx4 rb1 = *(const uintx4*)(bp0 + 64);

#define S23_MFMA(ASUB)                                                         \
    { _Pragma("unroll")                                                        \
      for (int ks = 0; ks < 2; ++ks) {                                         \
        short8 bf8 = *(const short8*)(ldsB + (wc * 16 + fr) * 72 + ks * 32 + fq * 8); \
        _Pragma("unroll")                                                      \
        for (int mi = 0; mi < 2; ++mi) {                                       \
            short8 af = *(const short8*)(ldsA + (wr * 32 + mi * 16 + fr) * 136 + (ASUB) + ks * 32 + fq * 8); \
            acc[mi] = __builtin_amdgcn_mfma_f32_16x16x32_bf16(af, bf8, acc[mi], 0, 0, 0); \
        }                                                                      \
      } }

    for (int it2 = 0; it2 < 4; ++it2) {
        bar_fast();
#pragma unroll
        for (int j = 0; j < 8; ++j) { int f = tid + 256 * j;
            *(ull*)(ldsA + (size_t)(f >> 5) * 136 + ((f & 31) << 2)) = apf[j]; }
        *(uintx4*)(ldsB + (tid >> 3) * 72 + ((tid & 7) << 3)) = rb0;
        bar_lds();
        if (it2 < 3) {
            int c2 = it2 + 1;
#pragma unroll
            for (int j = 0; j < 8; ++j) { int f = tid + 256 * j;
                apf[j] = a_ld64<COH>(Aq + (size_t)(f >> 5) * 256 + c2 * 32 + (f & 31)); }
            rb0 = *(const uintx4*)(bp0 + (2 * it2 + 2) * 64);
        }
        S23_MFMA(0);
        bar_fast();
        *(uintx4*)(ldsB + (tid >> 3) * 72 + ((tid & 7) << 3)) = rb1;
        bar_lds();
        if (it2 < 3) rb1 = *(const uintx4*)(bp0 + (2 * it2 + 3) * 64);
        S23_MFMA(64);
    }

#pragma unroll
    for (int mi = 0; mi < 2; ++mi)
#pragma unroll
        for (int j = 0; j < 4; ++j) {
            int row = rowg + wr * 32 + mi * 16 + fq * 4 + j;
            int col = col0 + wc * 16 + fr;
            float v = acc[mi][j] + bias[col];
            unsigned int ow = f2bf(elu1(v));
            unsigned int pr = __shfl_xor(ow, 1, 64);
            if (!(fr & 1))
                a_st<COH>((unsigned int*)(Z2_w + row * HID + z * FEAT + col), ow | (pr << 16));
        }
}

// ---------------------------------------------------------------------------
// S3: obs head -> out/loss (no Xbuf store); reward head. No downstream
// consumer inside the step -> runs after the s4f flag, overlapping skew.
// ---------------------------------------------------------------------------
template<bool COH>
__device__ __forceinline__ void s3_stage(const P& p, unsigned short* lds,
                                         int g, int m, int t,
                                         const unsigned short* Z2_r) {
    const int tid = threadIdx.x, lane = tid & 63, wv = tid >> 6;
    const int wr = wv & 1, wc = wv >> 1;
    const int fr = lane & 15, fq = lane >> 4;
    const int rowg = g * 64;

    if (m < 8) {
        const int col0 = m * 32;
        unsigned short* ldsA = lds;
        unsigned short* ldsB = lds + 64 * 136;
        floatx4 acc[2];
        floatx4 z4 = {0.f, 0.f, 0.f, 0.f};
        acc[0] = z4; acc[1] = z4;

        const ull* Aq = (const ull*)(Z2_r + (size_t)rowg * HID);   // obs half
        const unsigned short* Bg = p.W2o + (size_t)col0 * FEAT;

        ull apf[8];
#pragma unroll
        for (int j = 0; j < 8; ++j) { int f = tid + 256 * j;
            apf[j] = a_ld64<COH>(Aq + (size_t)(f >> 5) * 256 + (f & 31)); }
        const unsigned short* bp0 = Bg + (size_t)(tid >> 3) * FEAT + ((tid & 7) << 3);
        uintx4 rb0 = *(const uintx4*)(bp0);
        uintx4 rb1 = *(const uintx4*)(bp0 + 64);

        for (int it2 = 0; it2 < 4; ++it2) {
            bar_fast();
#pragma unroll
            for (int j = 0; j < 8; ++j) { int f = tid + 256 * j;
                *(ull*)(ldsA + (size_t)(f >> 5) * 136 + ((f & 31) << 2)) = apf[j]; }
            *(uintx4*)(ldsB + (tid >> 3) * 72 + ((tid & 7) << 3)) = rb0;
            bar_lds();
            if (it2 < 3) {
                int c2 = it2 + 1;
#pragma unroll
                for (int j = 0; j < 8; ++j) { int f = tid + 256 * j;
                    apf[j] = a_ld64<COH>(Aq + (size_t)(f >> 5) * 256 + c2 * 32 + (f & 31)); }
                rb0 = *(const uintx4*)(bp0 + (2 * it2 + 2) * 64);
            }
            S23_MFMA(0);
            bar_fast();
            *(uintx4*)(ldsB + (tid >> 3) * 72 + ((tid & 7) << 3)) = rb1;
            bar_lds();
            if (it2 < 3) rb1 = *(const uintx4*)(bp0 + (2 * it2 + 3) * 64);
            S23_MFMA(64);
        }

        const int col = col0 + wc * 16 + fr;
        const float b2oc = p.b2o[col];
        float lsum = 0.f;
#pragma unroll
        for (int mi = 0; mi < 2; ++mi)
#pragma unroll
            for (int j = 0; j < 4; ++j) {
                int row = rowg + wr * 32 + mi * 16 + fq * 4 + j;
                float mval = acc[mi][j] + b2oc;
                size_t oidx = (size_t)t * BATCH * OBS_DIM + (size_t)row * OBS_DIM + col;
                __builtin_nontemporal_store(mval, p.out + 1 + oidx);
                float d = __builtin_nontemporal_load(p.obs + oidx) - mval;
                lsum += d * d;
            }
#pragma unroll
        for (int off = 32; off > 0; off >>= 1) lsum += __shfl_down(lsum, off, 64);
        if (lane == 0) atomicAdd(p.accum + 0, lsum);
    } else if (m >= 16) {
        const int row = rowg + (m - 16) * 4 + wv;
        const ull* zq = (const ull*)(Z2_r + (size_t)row * HID + FEAT) + lane * 2;
        ull z0 = a_ld64<COH>(zq);
        ull z1 = a_ld64<COH>(zq + 1);
        short8 w8 = *(const short8*)(p.w2r + lane * 8);
        float s = 0.f;
#pragma unroll
        for (int k = 0; k < 4; ++k) {
            unsigned int u = (unsigned int)(z0 >> (16 * k)) & 0xFFFFu;
            s += bf2f(u) * bf2f((unsigned int)(unsigned short)w8[k]);
        }
#pragma unroll
        for (int k = 0; k < 4; ++k) {
            unsigned int u = (unsigned int)(z1 >> (16 * k)) & 0xFFFFu;
            s += bf2f(u) * bf2f((unsigned int)(unsigned short)w8[4 + k]);
        }
#pragma unroll
        for (int off = 32; off > 0; off >>= 1) s += __shfl_down(s, off, 64);
        if (lane == 0) {
            float mm = s + p.b2r[0];
            __builtin_nontemporal_store(
                mm, p.out + 1 + (size_t)T_STEPS * BATCH * OBS_DIM + (size_t)t * BATCH + row);
            float d = __builtin_nontemporal_load(p.reward + (size_t)t * BATCH + row) - mm;
            atomicAdd(p.accum + 1, d * d);
        }
    }
}

// ---------------------------------------------------------------------------
// S4F (fused GRU): gi = [Z2_obs | act] @ Wf^T + (b_ih + bf_fold) -> GRU.
// Main loop = S2's proven K512 schedule with B widened to 96 rows; K32 tail.
// ---------------------------------------------------------------------------
template<bool COH>
__device__ __forceinline__ void s4f_stage(const P& p, unsigned short* lds,
                                          int g, int m, int t,
                                          const unsigned short* Z2_r,
                                          const unsigned short* GHb_r,
                                          const float* h_r,
                                          float* h_w, unsigned short* hbf_w) {
    const int tid = threadIdx.x, lane = tid & 63, wv = tid >> 6;
    const int wr = wv & 1, wc = wv >> 1;
    const int fr = lane & 15, fq = lane >> 4;
    const int rowg = g * 64;
    const int col0 = m * 32;
    unsigned short* ldsA = lds;               // 64 x 136
    unsigned short* ldsB = lds + 64 * 136;    // 96 x 72

    floatx4 acc[3][2];
    floatx4 z4 = {0.f, 0.f, 0.f, 0.f};
#pragma unroll
    for (int g3 = 0; g3 < 3; ++g3) { acc[g3][0] = z4; acc[g3][1] = z4; }

    const ull* Aq = (const ull*)(Z2_r + (size_t)rowg * HID);   // obs half

    ull apf[8];
#pragma unroll
    for (int j = 0; j < 8; ++j) { int f = tid + 256 * j;
        apf[j] = a_ld64<COH>(Aq + (size_t)(f >> 5) * 256 + (f & 31)); }
    uintx4 rb0[3], rb1[3];
#pragma unroll
    for (int i = 0; i < 3; ++i) { int c = tid + 256 * i;
        int r = c >> 3, ko = (c & 7) << 3;
        const unsigned short* bp =
            p.Wf + (size_t)((r >> 5) * HID + col0 + (r & 31)) * KF + ko;
        rb0[i] = __builtin_nontemporal_load((const uintx4*)bp);
        rb1[i] = __builtin_nontemporal_load((const uintx4*)(bp + 64)); }

#define S4F_MFMA(ASUB)                                                         \
    { _Pragma("unroll")                                                        \
      for (int ks = 0; ks < 2; ++ks) {                                         \
        short8 af[2];                                                          \
        _Pragma("unroll")                                                      \
        for (int mi = 0; mi < 2; ++mi)                                         \
            af[mi] = *(const short8*)(ldsA + (wr * 32 + mi * 16 + fr) * 136 + (ASUB) + ks * 32 + fq * 8); \
        _Pragma("unroll")                                                      \
        for (int g3 = 0; g3 < 3; ++g3) {                                       \
            short8 bf8 = *(const short8*)(ldsB + (g3 * 32 + wc * 16 + fr) * 72 + ks * 32 + fq * 8); \
            _Pragma("unroll")                                                  \
            for (int mi = 0; mi < 2; ++mi)                                     \
                acc[g3][mi] = __builtin_amdgcn_mfma_f32_16x16x32_bf16(         \
                    af[mi], bf8, acc[g3][mi], 0, 0, 0);                        \
        }                                                                      \
      } }

    for (int it2 = 0; it2 < 4; ++it2) {
        bar_fast();
#pragma unroll
        for (int j = 0; j < 8; ++j) { int f = tid + 256 * j;
            *(ull*)(ldsA + (size_t)(f >> 5) * 136 + ((f & 31) << 2)) = apf[j]; }
#pragma unroll
        for (int i = 0; i < 3; ++i) { int c = tid + 256 * i;
            int r = c >> 3, ko = (c & 7) << 3;
            *(uintx4*)(ldsB + r * 72 + ko) = rb0[i]; }
        bar_lds();
        if (it2 < 3) {
            int c2 = it2 + 1;
#pragma unroll
            for (int j = 0; j < 8; ++j) { int f = tid + 256 * j;
                apf[j] = a_ld64<COH>(Aq + (size_t)(f >> 5) * 256 + c2 * 32 + (f & 31)); }
#pragma unroll
            for (int i = 0; i < 3; ++i) { int c = tid + 256 * i;
                int r = c >> 3, ko = (c & 7) << 3;
                rb0[i] = __builtin_nontemporal_load((const uintx4*)
                    (p.Wf + (size_t)((r >> 5) * HID + col0 + (r & 31)) * KF
                     + (2 * it2 + 2) * 64 + ko)); }
        }
        S4F_MFMA(0);
        bar_fast();
#pragma unroll
        for (int i = 0; i < 3; ++i) { int c = tid + 256 * i;
            int r = c >> 3, ko = (c & 7) << 3;
            *(uintx4*)(ldsB + r * 72 + ko) = rb1[i]; }
        bar_lds();
        if (it2 < 3) {
#pragma unroll
            for (int i = 0; i < 3; ++i) { int c = tid + 256 * i;
                int r = c >> 3, ko = (c & 7) << 3;
                rb1[i] = __builtin_nontemporal_load((const uintx4*)
                    (p.Wf + (size_t)((r >> 5) * HID + col0 + (r & 31)) * KF
                     + (2 * it2 + 3) * 64 + ko)); }
        }
        S4F_MFMA(64);
    }

    // ---- K32 action tail ----
    bar_fast();
    for (int e = tid; e < 64 * 32; e += 256) {
        int row = e >> 5, cc = e & 31;
        float av = __builtin_nontemporal_load(
            p.action + ((size_t)t * BATCH + rowg + row) * ACT_DIM + cc);
        ldsA[row * 136 + cc] = (unsigned short)f2bf(av);
    }
#pragma unroll
    for (int i = 0; i < 2; ++i) { int c = tid + 256 * i;
        if (c < 384) {
            int r = c >> 2, ko = (c & 3) << 3;
            *(uintx4*)(ldsB + r * 72 + ko) = __builtin_nontemporal_load((const uintx4*)
                (p.Wf + (size_t)((r >> 5) * HID + col0 + (r & 31)) * KF + 512 + ko));
        } }
    bar_lds();
    {
        short8 af[2];
#pragma unroll
        for (int mi = 0; mi < 2; ++mi)
            af[mi] = *(const short8*)(ldsA + (wr * 32 + mi * 16 + fr) * 136 + fq * 8);
#pragma unroll
        for (int g3 = 0; g3 < 3; ++g3) {
            short8 bf8 = *(const short8*)(ldsB + (g3 * 32 + wc * 16 + fr) * 72 + fq * 8);
#pragma unroll
            for (int mi = 0; mi < 2; ++mi)
                acc[g3][mi] = __builtin_amdgcn_mfma_f32_16x16x32_bf16(
                    af[mi], bf8, acc[g3][mi], 0, 0, 0);
        }
    }
#undef S4F_MFMA

    const int col = col0 + wc * 16 + fr;
    const float bir = p.b_ih[col]           + p.bf_fold[col];
    const float biz = p.b_ih[HID + col]     + p.bf_fold[HID + col];
    const float bin = p.b_ih[2 * HID + col] + p.bf_fold[2 * HID + col];
    float hrv[2][4], hzv[2][4], hnv[2][4], hpv[2][4];
    {
        const unsigned int* GW = (const unsigned int*)GHb_r;
        const int cw = col >> 1, hi = col & 1;
#pragma unroll
        for (int mi = 0; mi < 2; ++mi)
#pragma unroll
            for (int j = 0; j < 4; ++j) {
                int row = rowg + wr * 32 + mi * 16 + fq * 4 + j;
                unsigned int ur = a_ld<COH>(GW + (size_t)row * 1536 + cw);
                unsigned int uz = a_ld<COH>(GW + (size_t)row * 1536 + 512 + cw);
                unsigned int un = a_ld<COH>(GW + (size_t)row * 1536 + 1024 + cw);
                hrv[mi][j] = bf2f(hi ? (ur >> 16) : (ur & 0xFFFFu));
                hzv[mi][j] = bf2f(hi ? (uz >> 16) : (uz & 0xFFFFu));
                hnv[mi][j] = bf2f(hi ? (un >> 16) : (un & 0xFFFFu));
                hpv[mi][j] = __uint_as_float(a_ld<COH>((const unsigned int*)(h_r + (size_t)row * HID + col)));
            }
    }
#pragma unroll
    for (int mi = 0; mi < 2; ++mi)
#pragma unroll
        for (int j = 0; j < 4; ++j) {
            int row = rowg + wr * 32 + mi * 16 + fq * 4 + j;
            float r  = sigm(acc[0][mi][j] + bir + hrv[mi][j]);
            float z  = sigm(acc[1][mi][j] + biz + hzv[mi][j]);
            float nn = tanhf(acc[2][mi][j] + bin + r * hnv[mi][j]);
            float hv = (1.f - z) * nn + z * hpv[mi][j];
            a_st<COH>((unsigned int*)(h_w + (size_t)row * HID + col), __float_as_uint(hv));
            unsigned int ow = f2bf(hv);
            unsigned int pr = __shfl_xor(ow, 1, 64);
            if (!(fr & 1))
                a_st<COH>((unsigned int*)(hbf_w + row * HID + col), ow | (pr << 16));
        }
}

// ---------------------------------------------------------------------------
// S4 (unfused Wih path) — PROLOGUE ONLY: h0 = GRU([obs0,0], 0).
// ---------------------------------------------------------------------------
template<bool COH>
__device__ __forceinline__ void s4_stage(const P& p, unsigned short* lds,
                                         int g, int m,
                                         const unsigned short* Xbuf_r,
                                         float* h_w, unsigned short* hbf_w) {
    const int tid = threadIdx.x, lane = tid & 63, wv = tid >> 6;
    const int wr = wv & 1, wc = wv >> 1;
    const int fr = lane & 15, fq = lane >> 4;
    const int rowg = g * 64;
    const int col0 = m * 32;
    unsigned short* ldsA = lds;               // 64 x 104
    unsigned short* ldsB = lds + 64 * 104;    // 96 x 104

    floatx4 acc[3][2];
    floatx4 z4 = {0.f, 0.f, 0.f, 0.f};
#pragma unroll
    for (int g3 = 0; g3 < 3; ++g3) { acc[g3][0] = z4; acc[g3][1] = z4; }

    const ull* Xq = (const ull*)(Xbuf_r + (size_t)rowg * KIH);
    ull apf[6];
#pragma unroll
    for (int j = 0; j < 6; ++j) { int f = tid + 256 * j;
        apf[j] = a_ld64<COH>(Xq + (size_t)(f / 24) * 72 + (f % 24)); }

    uintx4 wpfA[5], wpfB[5];
#pragma unroll
    for (int j = 0; j < 5; ++j) { int f = tid + 256 * j;
        if (f < 1152) { int r = f / 12, ko = (f - r * 12) * 8;
            const unsigned short* wp =
                p.Wih + (size_t)((r >> 5) * HID + col0 + (r & 31)) * KIH + ko;
            wpfA[j] = __builtin_nontemporal_load((const uintx4*)wp);
            wpfB[j] = __builtin_nontemporal_load((const uintx4*)(wp + 96)); } }

#pragma unroll
    for (int c = 0; c < 3; ++c) {
        bar_fast();
#pragma unroll
        for (int j = 0; j < 6; ++j) { int f = tid + 256 * j;
            *(ull*)(ldsA + (size_t)(f / 24) * 104 + ((f % 24) << 2)) = apf[j]; }
#pragma unroll
        for (int j = 0; j < 5; ++j) { int f = tid + 256 * j;
            if (f < 1152) { int r = f / 12, ko = (f - r * 12) * 8;
                *(uintx4*)(ldsB + r * 104 + ko) = (c & 1) ? wpfB[j] : wpfA[j]; } }
        bar_lds();
        if (c < 2) {
#pragma unroll
            for (int j = 0; j < 6; ++j) { int f = tid + 256 * j;
                apf[j] = a_ld64<COH>(Xq + (size_t)(f / 24) * 72 + (c + 1) * 24 + (f % 24)); }
        }
        if (c == 0) {
#pragma unroll
            for (int j = 0; j < 5; ++j) { int f = tid + 256 * j;
                if (f < 1152) { int r = f / 12, ko = (f - r * 12) * 8;
                    wpfA[j] = __builtin_nontemporal_load((const uintx4*)
                        (p.Wih + (size_t)((r >> 5) * HID + col0 + (r & 31)) * KIH + 192 + ko)); } }
        }
#pragma unroll
        for (int ks = 0; ks < 3; ++ks) {
            short8 af[2];
#pragma unroll
            for (int mi = 0; mi < 2; ++mi)
                af[mi] = *(const short8*)(ldsA + (wr * 32 + mi * 16 + fr) * 104 + ks * 32 + fq * 8);
#pragma unroll
            for (int g3 = 0; g3 < 3; ++g3) {
                short8 bf8 = *(const short8*)(ldsB + (g3 * 32 + wc * 16 + fr) * 104 + ks * 32 + fq * 8);
#pragma unroll
                for (int mi = 0; mi < 2; ++mi)
                    acc[g3][mi] = __builtin_amdgcn_mfma_f32_16x16x32_bf16(
                        af[mi], bf8, acc[g3][mi], 0, 0, 0);
            }
        }
    }

    const int col = col0 + wc * 16 + fr;
    const float bir = p.b_ih[col];
    const float biz = p.b_ih[HID + col];
    const float bin = p.b_ih[2 * HID + col];
    const float br = p.b_hh[col], bz = p.b_hh[HID + col], bn = p.b_hh[2 * HID + col];
#pragma unroll
    for (int mi = 0; mi < 2; ++mi)
#pragma unroll
        for (int j = 0; j < 4; ++j) {
            int row = rowg + wr * 32 + mi * 16 + fq * 4 + j;
            float r  = sigm(acc[0][mi][j] + bir + br);
            float z  = sigm(acc[1][mi][j] + biz + bz);
            float nn = tanhf(acc[2][mi][j] + bin + r * bn);
            float hv = (1.f - z) * nn;
            a_st<COH>((unsigned int*)(h_w + (size_t)row * HID + col), __float_as_uint(hv));
            unsigned int ow = f2bf(hv);
            unsigned int pr = __shfl_xor(ow, 1, 64);
            if (!(fr & 1))
                a_st<COH>((unsigned int*)(hbf_w + row * HID + col), ow | (pr << 16));
        }
}

// ---------------------------------------------------------------------------
template<bool COH>
__device__ void rollout(const P& p, unsigned short* lds, int g, int m) {
    int* fbase = p.bar + 2048 + g * 512;
    int fep = 0;

    s4_stage<COH>(p, lds, g, m, p.Xbuf1, p.h[0], p.hbf);
    gbar_flags(fbase, m, fep);

    for (int t = 0; t < T_STEPS; ++t) {
        s1_stage<COH>(p, lds, g, m, p.hbf, p.Z1, p.GHb);
        gbar_flags(fbase, m, fep);
        s2_stage<COH>(p, lds, g, m, p.Z1, p.Z2);
        gbar_flags(fbase, m, fep);
        if (t < T_STEPS - 1) {
            s4f_stage<COH>(p, lds, g, m, t, p.Z2, p.GHb, p.h[t & 1],
                           p.h[(t + 1) & 1], p.hbf);
            fep++;
            arrive_flags(fbase, m, fep);
            s3_stage<COH>(p, lds, g, m, t, p.Z2);
            wait_flags(fbase, fep);
        } else {
            s3_stage<COH>(p, lds, g, m, t, p.Z2);
        }
    }
}

// ---------------------------------------------------------------------------
__global__ __launch_bounds__(256, 1) void k_persist(P p) {
    __shared__ unsigned short lds[17920];   // max: S1 = 64*136 + 128*72
    __shared__ int sh[3];

    const int bid = blockIdx.x;
    if (threadIdx.x == 0) {
        unsigned int xcd = __builtin_amdgcn_s_getreg(HWREG_XCC_ID) & 7u;
        int r = __hip_atomic_fetch_add(p.bar + 1024 + xcd, 1,
                                       __ATOMIC_RELAXED, __HIP_MEMORY_SCOPE_AGENT);
        sh[0] = (int)xcd; sh[1] = r;
    }
    int repoch = 0;
    gbar(p.bar + 1200, p.bar + 1264, repoch, NBLK);
    if (threadIdx.x == 0) {
        int ok = (sh[1] < 32);
        for (int i = 0; i < 8; ++i)
            ok &= (dev_ld((const unsigned int*)(p.bar + 1024 + i)) == 32u);
        sh[2] = ok;
    }
    __syncthreads();

    if (sh[2]) rollout<false>(p, lds, sh[0], sh[1]);
    else       rollout<true >(p, lds, bid & 7, bid >> 3);

    gbar(p.bar + 1200, p.bar + 1264, repoch, NBLK);
    if (bid == 0 && threadIdx.x == 0) {
        const float inv = 1.f / (float)(T_STEPS * BATCH);
        float a0 = dev_ldf(p.accum + 0);
        float a1 = dev_ldf(p.accum + 1);
        p.out[0] = 0.5f * a0 * inv + 128.f * LOG2PI
                 + 0.5f * a1 * inv + 0.5f * LOG2PI;
    }
}

// ---------------------------------------------------------------------------
__global__ void k_convert(
    const float* __restrict__ ow0, const float* __restrict__ rw0,
    const float* __restrict__ whh, const float* __restrict__ wih,
    const float* __restrict__ ow1, const float* __restrict__ rw1,
    const float* __restrict__ ow2, const float* __restrict__ rw2,
    const float* __restrict__ ob0, const float* __restrict__ rb0,
    const float* __restrict__ bhh, const float* __restrict__ ob2,
    unsigned short* __restrict__ Ws1, unsigned short* __restrict__ Wih,
    unsigned short* __restrict__ W1o, unsigned short* __restrict__ W1r,
    unsigned short* __restrict__ W2o, unsigned short* __restrict__ w2r,
    unsigned short* __restrict__ Wf,  float* __restrict__ bf_fold,
    float* __restrict__ bias_s1)
{
    const int i0 = blockIdx.x * 256 + threadIdx.x;
    const int stride = gridDim.x * 256;
    for (int i = i0; i < 4096 * 1024; i += stride) {
        int row = i >> 10;
        float v = (row < 512) ? ow0[i]
                : (row < 1024) ? rw0[i - 512 * 1024]
                               : whh[i - 1024 * 1024];
        Ws1[i] = (unsigned short)f2bf(v);
    }
    for (int i = i0; i < GDIM * KIH; i += stride) Wih[i] = (unsigned short)f2bf(wih[i]);
    for (int i = i0; i < FEAT * FEAT; i += stride) {
        W1o[i] = (unsigned short)f2bf(ow1[i]);
        W1r[i] = (unsigned short)f2bf(rw1[i]);
    }
    for (int i = i0; i < OBS_DIM * FEAT; i += stride) W2o[i] = (unsigned short)f2bf(ow2[i]);
    for (int i = i0; i < FEAT; i += stride) w2r[i] = (unsigned short)f2bf(rw2[i]);
    for (int i = i0; i < 4096; i += stride)
        bias_s1[i] = (i < 512) ? ob0[i] : (i < 1024) ? rb0[i - 512] : bhh[i - 1024];
    // Folded GRU weight: Wf[r][0:512] = Wih_obs(r).W2o ; Wf[r][512:544] = Wih_act(r)
    for (int i = i0; i < GDIM * 512; i += stride) {
        int r = i >> 9, f = i & 511;
        const float* wr_ = wih + (size_t)r * KIH;
        const float* w2c = ow2 + f;
        float s = 0.f;
        for (int o = 0; o < 256; ++o) s += wr_[o] * w2c[(size_t)o * 512];
        Wf[(size_t)r * KF + f] = (unsigned short)f2bf(s);
    }
    for (int i = i0; i < GDIM * 32; i += stride) {
        int r = i >> 5, c = i & 31;
        Wf[(size_t)r * KF + 512 + c] =
            (unsigned short)f2bf(wih[(size_t)r * KIH + 256 + c]);
    }
    for (int i = i0; i < GDIM; i += stride) {
        const float* wr_ = wih + (size_t)i * KIH;
        float s = 0.f;
        for (int o = 0; o < 256; ++o) s += wr_[o] * ob2[o];
        bf_fold[i] = s;
    }
}

__global__ void k_init(const float* __restrict__ obs,
                       unsigned short* __restrict__ Xbuf1,
                       float* __restrict__ accum,
                       int* __restrict__ bar)
{
    int i = blockIdx.x * 256 + threadIdx.x;
    if (i < BATCH * KIH) {
        int row = i / KIH, col = i - row * KIH;
        Xbuf1[i] = (col < OBS_DIM) ? (unsigned short)f2bf(obs[row * OBS_DIM + col])
                                   : (unsigned short)0;
    }
    if (i < 2)    accum[i] = 0.f;
    if (i < 8192) bar[i] = 0;
}

// ---------------------------------------------------------------------------
extern "C" void kernel_launch(void* const* d_in, const int* in_sizes, int n_in,
                              void* d_out, int out_size, void* d_ws, size_t ws_size,
                              hipStream_t stream)
{
    const float* obs      = (const float*)d_in[0];
    const float* action   = (const float*)d_in[1];
    const float* reward   = (const float*)d_in[2];
    const float* gru_w_ih = (const float*)d_in[3];
    const float* gru_w_hh = (const float*)d_in[4];
    const float* gru_b_ih = (const float*)d_in[5];
    const float* gru_b_hh = (const float*)d_in[6];
    const float* obs_w0   = (const float*)d_in[7];
    const float* obs_b0   = (const float*)d_in[8];
    const float* obs_w1   = (const float*)d_in[9];
    const float* obs_b1   = (const float*)d_in[10];
    const float* obs_w2   = (const float*)d_in[11];
    const float* obs_b2   = (const float*)d_in[12];
    const float* rew_w0   = (const float*)d_in[13];
    const float* rew_b0   = (const float*)d_in[14];
    const float* rew_w1   = (const float*)d_in[15];
    const float* rew_b1   = (const float*)d_in[16];
    const float* rew_w2   = (const float*)d_in[17];
    const float* rew_b2   = (const float*)d_in[18];

    char* ws = (char*)d_ws;
    auto alloc = [&](size_t bytes) -> char* {
        char* pr = ws;
        ws += (bytes + 255) & ~(size_t)255;
        return pr;
    };
    unsigned short* Ws1  = (unsigned short*)alloc((size_t)4096 * 1024 * 2);
    unsigned short* Wih  = (unsigned short*)alloc((size_t)GDIM * KIH * 2);
    unsigned short* W1o  = (unsigned short*)alloc((size_t)FEAT * FEAT * 2);
    unsigned short* W1r  = (unsigned short*)alloc((size_t)FEAT * FEAT * 2);
    unsigned short* W2o  = (unsigned short*)alloc((size_t)OBS_DIM * FEAT * 2);
    unsigned short* w2r  = (unsigned short*)alloc((size_t)FEAT * 2);
    unsigned short* Wf   = (unsigned short*)alloc((size_t)GDIM * KF * 2);
    float* bf_fold       = (float*)alloc((size_t)GDIM * 4);
    float* bias_s1       = (float*)alloc((size_t)4096 * 4);
    unsigned short* Z1   = (unsigned short*)alloc((size_t)BATCH * HID * 2);
    unsigned short* Z2   = (unsigned short*)alloc((size_t)BATCH * HID * 2);
    unsigned short* GHb  = (unsigned short*)alloc((size_t)BATCH * GDIM * 2);
    unsigned short* Xb1  = (unsigned short*)alloc((size_t)BATCH * KIH * 2);
    float* ha            = (float*)alloc((size_t)BATCH * HID * 4);
    float* hb            = (float*)alloc((size_t)BATCH * HID * 4);
    unsigned short* hf   = (unsigned short*)alloc((size_t)BATCH * HID * 2);
    float* accum         = (float*)alloc(256);
    int*   bar           = (int*)alloc(32768);

    k_convert<<<dim3(1024), dim3(256), 0, stream>>>(
        obs_w0, rew_w0, gru_w_hh, gru_w_ih, obs_w1, rew_w1, obs_w2, rew_w2,
        obs_b0, rew_b0, gru_b_hh, obs_b2,
        Ws1, Wih, W1o, W1r, W2o, w2r, Wf, bf_fold, bias_s1);

    k_init<<<dim3((BATCH * KIH + 255) / 256), dim3(256), 0, stream>>>(obs, Xb1, accum, bar);

    P hp;
    hp.obs = obs; hp.action = action; hp.reward = reward;
    hp.b_ih = gru_b_ih; hp.b_hh = gru_b_hh;
    hp.b1o = obs_b1; hp.b1r = rew_b1; hp.b2o = obs_b2; hp.b2r = rew_b2;
    hp.Ws1 = Ws1; hp.Wih = Wih; hp.W1o = W1o; hp.W1r = W1r;
    hp.W2o = W2o; hp.w2r = w2r; hp.Wf = Wf; hp.bf_fold = bf_fold;
    hp.bias_s1 = bias_s1;
    hp.Z1 = Z1; hp.Z2 = Z2; hp.Xbuf1 = Xb1;
    hp.hbf = hf; hp.GHb = GHb;
    hp.h[0] = ha; hp.h[1] = hb;
    hp.accum = accum; hp.out = (float*)d_out;
    hp.bar = bar;

    k_persist<<<dim3(NBLK), dim3(256), 0, stream>>>(hp);
}

// Round 8
// 2449.370 us; speedup vs baseline: 1.8233x; 1.8233x over previous
//
#include <hip/hip_runtime.h>
#include <stdint.h>

#define T_STEPS 64
#define BATCH   512
#define OBS_DIM 256
#define ACT_DIM 32
#define HID     1024
#define FEAT    512
#define GDIM    3072
#define KIH     288
#define NBLK    256
#define GMEMB   32          // blocks per group
#define LOG2PI  1.8378770664093453f
#define HWREG_XCC_ID 14356  // hwreg(id=20 XCC_ID, offset=0, size=8)

typedef __attribute__((ext_vector_type(8))) short  short8;   // 8 bf16
typedef __attribute__((ext_vector_type(4))) float  floatx4;  // MFMA C/D frag
typedef __attribute__((ext_vector_type(4))) unsigned int uintx4;
typedef unsigned long long ull;

__device__ __forceinline__ float bf2f(unsigned int u) {
    return __uint_as_float(u << 16);
}
__device__ __forceinline__ unsigned int f2bf(float f) {
    unsigned int u = __float_as_uint(f);
    return (u + 0x7FFFu + ((u >> 16) & 1u)) >> 16;  // RNE
}
__device__ __forceinline__ float elu1(float x)  { return x > 0.f ? x : expm1f(x); }
__device__ __forceinline__ float sigm(float x)  { return 1.f / (1.f + expf(-x)); }

// Coherent accessors — device scope.
__device__ __forceinline__ unsigned int dev_ld(const unsigned int* p) {
    return __hip_atomic_load(p, __ATOMIC_RELAXED, __HIP_MEMORY_SCOPE_AGENT);
}
__device__ __forceinline__ ull dev_ld64(const ull* p) {
    return __hip_atomic_load(p, __ATOMIC_RELAXED, __HIP_MEMORY_SCOPE_AGENT);
}
__device__ __forceinline__ void dev_st(unsigned int* p, unsigned int v) {
    __hip_atomic_store(p, v, __ATOMIC_RELAXED, __HIP_MEMORY_SCOPE_AGENT);
}
__device__ __forceinline__ float dev_ldf(const float* p) {
    return __uint_as_float(dev_ld((const unsigned int*)p));
}

template<bool COH>
__device__ __forceinline__ unsigned int a_ld(const unsigned int* p) {
    return COH ? dev_ld(p) : *p;
}
template<bool COH>
__device__ __forceinline__ ull a_ld64(const ull* p) {
    return COH ? dev_ld64(p) : *p;
}
template<bool COH>
__device__ __forceinline__ void a_st(unsigned int* p, unsigned int v) {
    if (COH) dev_st(p, v); else *p = v;
}

struct ParamsReal {
    const float* obs; const float* action; const float* reward;
    const float* b_ih; const float* b_hh;
    const float* b1o; const float* b1r; const float* b2o; const float* b2r;
    const unsigned short* Ws1; const unsigned short* Wih;
    const unsigned short* W1o; const unsigned short* W1r;
    const unsigned short* W2o; const unsigned short* w2r;
    const float* bias_s1;
    unsigned short* Z1[2]; unsigned short* Z2[2]; unsigned short* Xbuf[2];
    unsigned short* hbf[2]; unsigned short* GHb[2]; float* h[2];
    float* accum; float* out;
    int* bar;
};
#define P ParamsReal

// ---------------------------------------------------------------------------
// Raw block barriers (no compiler vmcnt(0) drain): keep global register
// prefetches in flight across the barrier.
// ---------------------------------------------------------------------------
__device__ __forceinline__ void bar_fast() {
    asm volatile("" ::: "memory");
    __builtin_amdgcn_s_barrier();
    asm volatile("" ::: "memory");
}
__device__ __forceinline__ void bar_lds() {
    asm volatile("s_waitcnt lgkmcnt(0)" ::: "memory");
    __builtin_amdgcn_s_barrier();
    asm volatile("" ::: "memory");
}

// ---------------------------------------------------------------------------
// Atomic-counter barrier — entry/exit rendezvous only.
// ---------------------------------------------------------------------------
__device__ __forceinline__ void gbar(int* cnt, int* gen, int& epoch, int members) {
    __syncthreads();
    if (threadIdx.x == 0) {
        __builtin_amdgcn_fence(__ATOMIC_RELEASE, "workgroup");
        epoch++;
        int prev = __hip_atomic_fetch_add(cnt, 1, __ATOMIC_RELAXED,
                                          __HIP_MEMORY_SCOPE_AGENT);
        if (prev == members * epoch - 1) {
            __hip_atomic_store(gen, epoch, __ATOMIC_RELAXED,
                               __HIP_MEMORY_SCOPE_AGENT);
        } else {
            while (__hip_atomic_load(gen, __ATOMIC_RELAXED,
                                     __HIP_MEMORY_SCOPE_AGENT) < epoch)
                __builtin_amdgcn_s_sleep(2);
        }
        __builtin_amdgcn_fence(__ATOMIC_ACQUIRE, "workgroup");
    }
    __syncthreads();
}

// ---------------------------------------------------------------------------
// Flag-array group barrier (32 blocks): per-block 64B-padded epoch slot (no
// RMW serialization, no gen broadcast round-trip). Wave 0's lanes poll all
// 32 slots in parallel; exec-mask convergence = the all() reduction.
// __syncthreads first drains vmcnt -> data stores are at their cache
// destination before the flag is posted. s_sleep(1) for fast wakeup.
// ---------------------------------------------------------------------------
__device__ __forceinline__ void gbar_flags(int* fbase, int m, int& epoch) {
    __syncthreads();
    epoch++;
    if (threadIdx.x == 0) {
        __builtin_amdgcn_fence(__ATOMIC_RELEASE, "workgroup");
        dev_st((unsigned int*)(fbase + m * 16), (unsigned int)epoch);
    }
    if (threadIdx.x < 64) {
        const unsigned int* fp =
            (const unsigned int*)(fbase + (threadIdx.x & 31) * 16);
        while ((int)dev_ld(fp) < epoch) __builtin_amdgcn_s_sleep(1);
        __builtin_amdgcn_fence(__ATOMIC_ACQUIRE, "workgroup");
    }
    __syncthreads();
}

// ---------------------------------------------------------------------------
// S1: C[64 x 4096] = hbf_r[g] @ Ws1^T + bias. tile 64x128, K=1024.
// B stream nontemporal + 2-deep prefetch (rb0/rb1). (2542us R1 verbatim)
// ---------------------------------------------------------------------------
template<bool COH>
__device__ __forceinline__ void s1_stage(const P& p, unsigned short* lds,
                                         int g, int m,
                                         const unsigned short* hbf_r,
                                         unsigned short* Z1_w,
                                         unsigned short* GHb_w) {
    const int tid = threadIdx.x, lane = tid & 63, wv = tid >> 6;
    const int wr = wv & 1, wc = wv >> 1, fr = lane & 15, fq = lane >> 4;
    const int rowg = g * 64, col0 = m * 128;
    unsigned short* ldsA = lds;               // 64 x 136
    unsigned short* ldsB = lds + 64 * 136;    // 128 x 72

    floatx4 acc[2][4];
    floatx4 z4 = {0.f, 0.f, 0.f, 0.f};
#pragma unroll
    for (int mi = 0; mi < 2; ++mi)
#pragma unroll
        for (int n = 0; n < 4; ++n) acc[mi][n] = z4;

    const ull* Aq = (const ull*)(hbf_r + (size_t)rowg * HID);   // row = 256 u64
    const unsigned short* Bg = p.Ws1 + (size_t)col0 * HID;

    ull apf[8];
#pragma unroll
    for (int j = 0; j < 8; ++j) { int f = tid + 256 * j;
        apf[j] = a_ld64<COH>(Aq + (size_t)(f >> 5) * 256 + (f & 31)); }
    uintx4 rb0[4], rb1[4];
#pragma unroll
    for (int i = 0; i < 4; ++i) { int c = tid + 256 * i;
        const unsigned short* bp = Bg + (size_t)(c >> 3) * HID + ((c & 7) << 3);
        rb0[i] = __builtin_nontemporal_load((const uintx4*)bp);
        rb1[i] = __builtin_nontemporal_load((const uintx4*)(bp + 64)); }

#define S1_MFMA(ASUB)                                                          \
    {                                                                          \
        _Pragma("unroll")                                                      \
        for (int ks = 0; ks < 2; ++ks) {                                       \
            short8 af[2], bf8[4];                                              \
            _Pragma("unroll")                                                  \
            for (int mi = 0; mi < 2; ++mi)                                     \
                af[mi] = *(const short8*)(ldsA + (wr * 32 + mi * 16 + fr) * 136 + (ASUB) + ks * 32 + fq * 8); \
            _Pragma("unroll")                                                  \
            for (int n = 0; n < 4; ++n)                                        \
                bf8[n] = *(const short8*)(ldsB + (wc * 64 + n * 16 + fr) * 72 + ks * 32 + fq * 8); \
            _Pragma("unroll")                                                  \
            for (int mi = 0; mi < 2; ++mi)                                     \
                _Pragma("unroll")                                              \
                for (int n = 0; n < 4; ++n)                                    \
                    acc[mi][n] = __builtin_amdgcn_mfma_f32_16x16x32_bf16(      \
                        af[mi], bf8[n], acc[mi][n], 0, 0, 0);                  \
        }                                                                      \
    }

    for (int it2 = 0; it2 < 8; ++it2) {
        // ---- even iteration (it = 2*it2): stage A chunk + B(rb0) ----
        bar_fast();
#pragma unroll
        for (int j = 0; j < 8; ++j) { int f = tid + 256 * j;
            *(ull*)(ldsA + (size_t)(f >> 5) * 136 + ((f & 31) << 2)) = apf[j]; }
#pragma unroll
        for (int i = 0; i < 4; ++i) { int c = tid + 256 * i;
            *(uintx4*)(ldsB + (c >> 3) * 72 + ((c & 7) << 3)) = rb0[i]; }
        bar_lds();
        if (it2 < 7) {
            int c2 = it2 + 1;
#pragma unroll
            for (int j = 0; j < 8; ++j) { int f = tid + 256 * j;
                apf[j] = a_ld64<COH>(Aq + (size_t)(f >> 5) * 256 + c2 * 32 + (f & 31)); }
            int k0n = (2 * it2 + 2) * 64;
#pragma unroll
            for (int i = 0; i < 4; ++i) { int c = tid + 256 * i;
                rb0[i] = __builtin_nontemporal_load((const uintx4*)
                    (Bg + (size_t)(c >> 3) * HID + k0n + ((c & 7) << 3))); }
        }
        S1_MFMA(0);
        // ---- odd iteration (it = 2*it2+1): stage B(rb1) ----
        bar_fast();
#pragma unroll
        for (int i = 0; i < 4; ++i) { int c = tid + 256 * i;
            *(uintx4*)(ldsB + (c >> 3) * 72 + ((c & 7) << 3)) = rb1[i]; }
        bar_lds();
        if (it2 < 7) {
            int k0n = (2 * it2 + 3) * 64;
#pragma unroll
            for (int i = 0; i < 4; ++i) { int c = tid + 256 * i;
                rb1[i] = __builtin_nontemporal_load((const uintx4*)
                    (Bg + (size_t)(c >> 3) * HID + k0n + ((c & 7) << 3))); }
        }
        S1_MFMA(64);
    }
#undef S1_MFMA

    const bool isZ1 = (col0 < 1024);
#pragma unroll
    for (int mi = 0; mi < 2; ++mi)
#pragma unroll
        for (int n = 0; n < 4; ++n)
#pragma unroll
            for (int j = 0; j < 4; ++j) {
                int row = rowg + wr * 32 + mi * 16 + fq * 4 + j;
                int col = col0 + wc * 64 + n * 16 + fr;
                float v = acc[mi][n][j] + p.bias_s1[col];
                unsigned int ow = f2bf(isZ1 ? elu1(v) : v);
                unsigned int pr = __shfl_xor(ow, 1, 64);
                if (!(fr & 1)) {
                    unsigned int pk = ow | (pr << 16);
                    if (isZ1)
                        a_st<COH>((unsigned int*)(Z1_w + row * HID + col), pk);
                    else
                        a_st<COH>((unsigned int*)GHb_w + (size_t)row * 1536 + ((col - 1024) >> 1), pk);
                }
            }
}

// ---------------------------------------------------------------------------
// S2: Z2 = elu(Z1 half @ W1z^T + b). z=m>>4, col0=(m&15)*32. K=512.
// W1 stays L2-resident (normal loads); 2-deep B prefetch; raw barriers.
// ---------------------------------------------------------------------------
template<bool COH>
__device__ __forceinline__ void s2_stage(const P& p, unsigned short* lds,
                                         int g, int m,
                                         const unsigned short* Z1_r,
                                         unsigned short* Z2_w) {
    const int tid = threadIdx.x, lane = tid & 63, wv = tid >> 6;
    const int wr = wv & 1, wc = wv >> 1, fr = lane & 15, fq = lane >> 4;
    const int rowg = g * 64;
    const int z = m >> 4, col0 = (m & 15) * 32;
    unsigned short* ldsA = lds;               // 64 x 136
    unsigned short* ldsB = lds + 64 * 136;    // 32 x 72

    floatx4 acc[2];
    floatx4 z4 = {0.f, 0.f, 0.f, 0.f};
    acc[0] = z4; acc[1] = z4;

    const ull* Aq = (const ull*)(Z1_r + (size_t)rowg * HID + z * FEAT);
    const unsigned short* Bg = (z ? p.W1r : p.W1o) + (size_t)col0 * FEAT;
    const float* bias = z ? p.b1r : p.b1o;

    ull apf[8];
#pragma unroll
    for (int j = 0; j < 8; ++j) { int f = tid + 256 * j;
        apf[j] = a_ld64<COH>(Aq + (size_t)(f >> 5) * 256 + (f & 31)); }
    const unsigned short* bp0 = Bg + (size_t)(tid >> 3) * FEAT + ((tid & 7) << 3);
    uintx4 rb0 = *(const uintx4*)(bp0);
    uintx4 rb1 = *(const uintx4*)(bp0 + 64);

#define S23_MFMA(ASUB)                                                         \
    { _Pragma("unroll")                                                        \
      for (int ks = 0; ks < 2; ++ks) {                                         \
        short8 bf8 = *(const short8*)(ldsB + (wc * 16 + fr) * 72 + ks * 32 + fq * 8); \
        _Pragma("unroll")                                                      \
        for (int mi = 0; mi < 2; ++mi) {                                       \
            short8 af = *(const short8*)(ldsA + (wr * 32 + mi * 16 + fr) * 136 + (ASUB) + ks * 32 + fq * 8); \
            acc[mi] = __builtin_amdgcn_mfma_f32_16x16x32_bf16(af, bf8, acc[mi], 0, 0, 0); \
        }                                                                      \
      } }

    for (int it2 = 0; it2 < 4; ++it2) {
        bar_fast();
#pragma unroll
        for (int j = 0; j < 8; ++j) { int f = tid + 256 * j;
            *(ull*)(ldsA + (size_t)(f >> 5) * 136 + ((f & 31) << 2)) = apf[j]; }
        *(uintx4*)(ldsB + (tid >> 3) * 72 + ((tid & 7) << 3)) = rb0;
        bar_lds();
        if (it2 < 3) {
            int c2 = it2 + 1;
#pragma unroll
            for (int j = 0; j < 8; ++j) { int f = tid + 256 * j;
                apf[j] = a_ld64<COH>(Aq + (size_t)(f >> 5) * 256 + c2 * 32 + (f & 31)); }
            rb0 = *(const uintx4*)(bp0 + (2 * it2 + 2) * 64);
        }
        S23_MFMA(0);
        bar_fast();
        *(uintx4*)(ldsB + (tid >> 3) * 72 + ((tid & 7) << 3)) = rb1;
        bar_lds();
        if (it2 < 3) rb1 = *(const uintx4*)(bp0 + (2 * it2 + 3) * 64);
        S23_MFMA(64);
    }

#pragma unroll
    for (int mi = 0; mi < 2; ++mi)
#pragma unroll
        for (int j = 0; j < 4; ++j) {
            int row = rowg + wr * 32 + mi * 16 + fq * 4 + j;
            int col = col0 + wc * 16 + fr;
            float v = acc[mi][j] + bias[col];
            unsigned int ow = f2bf(elu1(v));
            unsigned int pr = __shfl_xor(ow, 1, 64);
            if (!(fr & 1))
                a_st<COH>((unsigned int*)(Z2_w + row * HID + z * FEAT + col), ow | (pr << 16));
        }
}

// ---------------------------------------------------------------------------
// S3: m<8: obs head tile 64x32, K=512 -> out/Xbuf/loss. m==8: act copy.
//     m>=16: reward head, 4 rows (1 per wave).
// ---------------------------------------------------------------------------
template<bool COH>
__device__ __forceinline__ void s3_stage(const P& p, unsigned short* lds,
                                         int g, int m, int t,
                                         const unsigned short* Z2_r,
                                         unsigned short* Xbuf_w) {
    const int tid = threadIdx.x, lane = tid & 63, wv = tid >> 6;
    const int wr = wv & 1, wc = wv >> 1;
    const int fr = lane & 15, fq = lane >> 4;
    const int rowg = g * 64;

    if (m < 8) {
        const int col0 = m * 32;
        unsigned short* ldsA = lds;
        unsigned short* ldsB = lds + 64 * 136;
        floatx4 acc[2];
        floatx4 z4 = {0.f, 0.f, 0.f, 0.f};
        acc[0] = z4; acc[1] = z4;

        const ull* Aq = (const ull*)(Z2_r + (size_t)rowg * HID);   // obs half
        const unsigned short* Bg = p.W2o + (size_t)col0 * FEAT;

        ull apf[8];
#pragma unroll
        for (int j = 0; j < 8; ++j) { int f = tid + 256 * j;
            apf[j] = a_ld64<COH>(Aq + (size_t)(f >> 5) * 256 + (f & 31)); }
        const unsigned short* bp0 = Bg + (size_t)(tid >> 3) * FEAT + ((tid & 7) << 3);
        uintx4 rb0 = *(const uintx4*)(bp0);
        uintx4 rb1 = *(const uintx4*)(bp0 + 64);

        for (int it2 = 0; it2 < 4; ++it2) {
            bar_fast();
#pragma unroll
            for (int j = 0; j < 8; ++j) { int f = tid + 256 * j;
                *(ull*)(ldsA + (size_t)(f >> 5) * 136 + ((f & 31) << 2)) = apf[j]; }
            *(uintx4*)(ldsB + (tid >> 3) * 72 + ((tid & 7) << 3)) = rb0;
            bar_lds();
            if (it2 < 3) {
                int c2 = it2 + 1;
#pragma unroll
                for (int j = 0; j < 8; ++j) { int f = tid + 256 * j;
                    apf[j] = a_ld64<COH>(Aq + (size_t)(f >> 5) * 256 + c2 * 32 + (f & 31)); }
                rb0 = *(const uintx4*)(bp0 + (2 * it2 + 2) * 64);
            }
            S23_MFMA(0);
            bar_fast();
            *(uintx4*)(ldsB + (tid >> 3) * 72 + ((tid & 7) << 3)) = rb1;
            bar_lds();
            if (it2 < 3) rb1 = *(const uintx4*)(bp0 + (2 * it2 + 3) * 64);
            S23_MFMA(64);
        }

        const int col = col0 + wc * 16 + fr;
        const float b2oc = p.b2o[col];
        float lsum = 0.f;
#pragma unroll
        for (int mi = 0; mi < 2; ++mi)
#pragma unroll
            for (int j = 0; j < 4; ++j) {
                int row = rowg + wr * 32 + mi * 16 + fq * 4 + j;
                float mval = acc[mi][j] + b2oc;
                size_t oidx = (size_t)t * BATCH * OBS_DIM + (size_t)row * OBS_DIM + col;
                __builtin_nontemporal_store(mval, p.out + 1 + oidx);
                unsigned int ow = f2bf(mval);
                unsigned int pr = __shfl_xor(ow, 1, 64);
                if (!(fr & 1))
                    a_st<COH>((unsigned int*)(Xbuf_w + row * KIH + col), ow | (pr << 16));
                float d = __builtin_nontemporal_load(p.obs + oidx) - mval;
                lsum += d * d;
            }
#pragma unroll
        for (int off = 32; off > 0; off >>= 1) lsum += __shfl_down(lsum, off, 64);
        if (lane == 0) atomicAdd(p.accum + 0, lsum);
    } else if (m == 8) {
        for (int e = tid; e < 64 * 16; e += 256) {
            int row = rowg + (e >> 4), cp = (e & 15) * 2;
            const float* ap = p.action + ((size_t)t * BATCH + row) * ACT_DIM + cp;
            unsigned int lo = f2bf(__builtin_nontemporal_load(ap));
            unsigned int hi = f2bf(__builtin_nontemporal_load(ap + 1));
            a_st<COH>((unsigned int*)(Xbuf_w + row * KIH + OBS_DIM + cp), lo | (hi << 16));
        }
    } else if (m >= 16) {
        const int row = rowg + (m - 16) * 4 + wv;
        const ull* zq = (const ull*)(Z2_r + (size_t)row * HID + FEAT) + lane * 2;
        ull z0 = a_ld64<COH>(zq);
        ull z1 = a_ld64<COH>(zq + 1);
        short8 w8 = *(const short8*)(p.w2r + lane * 8);
        float s = 0.f;
#pragma unroll
        for (int k = 0; k < 4; ++k) {
            unsigned int u = (unsigned int)(z0 >> (16 * k)) & 0xFFFFu;
            s += bf2f(u) * bf2f((unsigned int)(unsigned short)w8[k]);
        }
#pragma unroll
        for (int k = 0; k < 4; ++k) {
            unsigned int u = (unsigned int)(z1 >> (16 * k)) & 0xFFFFu;
            s += bf2f(u) * bf2f((unsigned int)(unsigned short)w8[4 + k]);
        }
#pragma unroll
        for (int off = 32; off > 0; off >>= 1) s += __shfl_down(s, off, 64);
        if (lane == 0) {
            float mm = s + p.b2r[0];
            __builtin_nontemporal_store(
                mm, p.out + 1 + (size_t)T_STEPS * BATCH * OBS_DIM + (size_t)t * BATCH + row);
            float d = __builtin_nontemporal_load(p.reward + (size_t)t * BATCH + row) - mm;
            atomicAdd(p.accum + 1, d * d);
        }
    }
}

// ---------------------------------------------------------------------------
// S4: gi = Xbuf_r[g rows] @ Wih^T (3 gates) -> GRU -> h_w, hbf_w.
// Wih stream nontemporal + 2-deep register prefetch. (2542us R1 verbatim)
// ---------------------------------------------------------------------------
template<bool COH>
__device__ __forceinline__ void s4_stage(const P& p, unsigned short* lds,
                                         int g, int m, int use_gh,
                                         const unsigned short* Xbuf_r,
                                         const unsigned short* GHb_r,
                                         const float* h_r,
                                         float* h_w, unsigned short* hbf_w) {
    const int tid = threadIdx.x, lane = tid & 63, wv = tid >> 6;
    const int wr = wv & 1, wc = wv >> 1;
    const int fr = lane & 15, fq = lane >> 4;
    const int rowg = g * 64;
    const int col0 = m * 32;
    unsigned short* ldsA = lds;               // 64 x 104
    unsigned short* ldsB = lds + 64 * 104;    // 96 x 104

    floatx4 acc[3][2];
    floatx4 z4 = {0.f, 0.f, 0.f, 0.f};
#pragma unroll
    for (int g3 = 0; g3 < 3; ++g3) { acc[g3][0] = z4; acc[g3][1] = z4; }

    const ull* Xq = (const ull*)(Xbuf_r + (size_t)rowg * KIH);   // row = 72 u64
    ull apf[6];
#pragma unroll
    for (int j = 0; j < 6; ++j) { int f = tid + 256 * j;
        apf[j] = a_ld64<COH>(Xq + (size_t)(f / 24) * 72 + (f % 24)); }

    uintx4 wpfA[5], wpfB[5];
#pragma unroll
    for (int j = 0; j < 5; ++j) { int f = tid + 256 * j;
        if (f < 1152) { int r = f / 12, ko = (f - r * 12) * 8;
            const unsigned short* wp =
                p.Wih + (size_t)((r >> 5) * HID + col0 + (r & 31)) * KIH + ko;
            wpfA[j] = __builtin_nontemporal_load((const uintx4*)wp);
            wpfB[j] = __builtin_nontemporal_load((const uintx4*)(wp + 96)); } }

#pragma unroll
    for (int c = 0; c < 3; ++c) {
        bar_fast();
#pragma unroll
        for (int j = 0; j < 6; ++j) { int f = tid + 256 * j;
            *(ull*)(ldsA + (size_t)(f / 24) * 104 + ((f % 24) << 2)) = apf[j]; }
#pragma unroll
        for (int j = 0; j < 5; ++j) { int f = tid + 256 * j;
            if (f < 1152) { int r = f / 12, ko = (f - r * 12) * 8;
                *(uintx4*)(ldsB + r * 104 + ko) = (c & 1) ? wpfB[j] : wpfA[j]; } }
        bar_lds();
        if (c < 2) {
#pragma unroll
            for (int j = 0; j < 6; ++j) { int f = tid + 256 * j;
                apf[j] = a_ld64<COH>(Xq + (size_t)(f / 24) * 72 + (c + 1) * 24 + (f % 24)); }
        }
        if (c == 0) {   // chunk 2 -> wpfA (consumed at c==2)
#pragma unroll
            for (int j = 0; j < 5; ++j) { int f = tid + 256 * j;
                if (f < 1152) { int r = f / 12, ko = (f - r * 12) * 8;
                    wpfA[j] = __builtin_nontemporal_load((const uintx4*)
                        (p.Wih + (size_t)((r >> 5) * HID + col0 + (r & 31)) * KIH + 192 + ko)); } }
        }
#pragma unroll
        for (int ks = 0; ks < 3; ++ks) {
            short8 af[2];
#pragma unroll
            for (int mi = 0; mi < 2; ++mi)
                af[mi] = *(const short8*)(ldsA + (wr * 32 + mi * 16 + fr) * 104 + ks * 32 + fq * 8);
#pragma unroll
            for (int g3 = 0; g3 < 3; ++g3) {
                short8 bf8 = *(const short8*)(ldsB + (g3 * 32 + wc * 16 + fr) * 104 + ks * 32 + fq * 8);
#pragma unroll
                for (int mi = 0; mi < 2; ++mi)
                    acc[g3][mi] = __builtin_amdgcn_mfma_f32_16x16x32_bf16(
                        af[mi], bf8, acc[g3][mi], 0, 0, 0);
            }
        }
    }

    const int col = col0 + wc * 16 + fr;
    const float bir = p.b_ih[col];
    const float biz = p.b_ih[HID + col];
    const float bin = p.b_ih[2 * HID + col];
    float hrv[2][4], hzv[2][4], hnv[2][4], hpv[2][4];
    if (use_gh) {
        const unsigned int* GW = (const unsigned int*)GHb_r;
        const int cw = col >> 1, hi = col & 1;
#pragma unroll
        for (int mi = 0; mi < 2; ++mi)
#pragma unroll
            for (int j = 0; j < 4; ++j) {
                int row = rowg + wr * 32 + mi * 16 + fq * 4 + j;
                unsigned int ur = a_ld<COH>(GW + (size_t)row * 1536 + cw);
                unsigned int uz = a_ld<COH>(GW + (size_t)row * 1536 + 512 + cw);
                unsigned int un = a_ld<COH>(GW + (size_t)row * 1536 + 1024 + cw);
                hrv[mi][j] = bf2f(hi ? (ur >> 16) : (ur & 0xFFFFu));
                hzv[mi][j] = bf2f(hi ? (uz >> 16) : (uz & 0xFFFFu));
                hnv[mi][j] = bf2f(hi ? (un >> 16) : (un & 0xFFFFu));
                hpv[mi][j] = __uint_as_float(a_ld<COH>((const unsigned int*)(h_r + (size_t)row * HID + col)));
            }
    } else {
        float br = p.b_hh[col], bz = p.b_hh[HID + col], bn = p.b_hh[2 * HID + col];
#pragma unroll
        for (int mi = 0; mi < 2; ++mi)
#pragma unroll
            for (int j = 0; j < 4; ++j) {
                hrv[mi][j] = br; hzv[mi][j] = bz; hnv[mi][j] = bn; hpv[mi][j] = 0.f;
            }
    }
#pragma unroll
    for (int mi = 0; mi < 2; ++mi)
#pragma unroll
        for (int j = 0; j < 4; ++j) {
            int row = rowg + wr * 32 + mi * 16 + fq * 4 + j;
            float r  = sigm(acc[0][mi][j] + bir + hrv[mi][j]);
            float z  = sigm(acc[1][mi][j] + biz + hzv[mi][j]);
            float nn = tanhf(acc[2][mi][j] + bin + r * hnv[mi][j]);
            float hv = (1.f - z) * nn + z * hpv[mi][j];
            a_st<COH>((unsigned int*)(h_w + (size_t)row * HID + col), __float_as_uint(hv));
            unsigned int ow = f2bf(hv);
            unsigned int pr = __shfl_xor(ow, 1, 64);
            if (!(fr & 1))
                a_st<COH>((unsigned int*)(hbf_w + row * HID + col), ow | (pr << 16));
        }
}

// ---------------------------------------------------------------------------
template<bool COH>
__device__ void rollout(const P& p, unsigned short* lds, int g, int m) {
    int* fbase = p.bar + 2048 + g * 512;
    int fep = 0;

    // h0 = GRU([obs0,0], 0): reads Xbuf[1] (k_init), writes h[0]/hbf[0]
    s4_stage<COH>(p, lds, g, m, 0, p.Xbuf[1], p.GHb[0], p.h[0], p.h[0], p.hbf[0]);
    gbar_flags(fbase, m, fep);

    for (int t = 0; t < T_STEPS; ++t) {
        const int pr = t & 1, nx = (t + 1) & 1;
        s1_stage<COH>(p, lds, g, m, p.hbf[pr], p.Z1[pr], p.GHb[pr]);
        gbar_flags(fbase, m, fep);
        s2_stage<COH>(p, lds, g, m, p.Z1[pr], p.Z2[pr]);
        gbar_flags(fbase, m, fep);
        s3_stage<COH>(p, lds, g, m, t, p.Z2[pr], p.Xbuf[pr]);
        gbar_flags(fbase, m, fep);
        if (t < T_STEPS - 1) {
            s4_stage<COH>(p, lds, g, m, 1, p.Xbuf[pr], p.GHb[pr], p.h[pr],
                          p.h[nx], p.hbf[nx]);
            gbar_flags(fbase, m, fep);
        }
    }
}

// ---------------------------------------------------------------------------
// Persistent rollout, 256 blocks x 256 threads, 1 block/CU. Blocks
// self-organize into 8 groups by MEASURED XCD; plain XCD-L2-cached
// activation path when uniform (32/XCD), device-coherent fallback otherwise.
// ---------------------------------------------------------------------------
__global__ __launch_bounds__(256, 1) void k_persist(P p) {
    __shared__ unsigned short lds[17920];   // max: S1 = 64*136 + 128*72
    __shared__ int sh[3];                   // g, m, ok

    const int bid = blockIdx.x;
    if (threadIdx.x == 0) {
        unsigned int xcd = __builtin_amdgcn_s_getreg(HWREG_XCC_ID) & 7u;
        int r = __hip_atomic_fetch_add(p.bar + 1024 + xcd, 1,
                                       __ATOMIC_RELAXED, __HIP_MEMORY_SCOPE_AGENT);
        sh[0] = (int)xcd; sh[1] = r;
    }
    int repoch = 0;
    gbar(p.bar + 1200, p.bar + 1264, repoch, NBLK);
    if (threadIdx.x == 0) {
        int ok = (sh[1] < 32);
        for (int i = 0; i < 8; ++i)
            ok &= (dev_ld((const unsigned int*)(p.bar + 1024 + i)) == 32u);
        sh[2] = ok;
    }
    __syncthreads();

    if (sh[2]) rollout<false>(p, lds, sh[0], sh[1]);       // fast: XCD-local
    else       rollout<true >(p, lds, bid & 7, bid >> 3);  // coherent fallback

    gbar(p.bar + 1200, p.bar + 1264, repoch, NBLK);
    if (bid == 0 && threadIdx.x == 0) {
        const float inv = 1.f / (float)(T_STEPS * BATCH);
        float a0 = dev_ldf(p.accum + 0);
        float a1 = dev_ldf(p.accum + 1);
        p.out[0] = 0.5f * a0 * inv + 128.f * LOG2PI
                 + 0.5f * a1 * inv + 0.5f * LOG2PI;
    }
}

// ---------------------------------------------------------------------------
__global__ void k_convert(
    const float* __restrict__ ow0, const float* __restrict__ rw0,
    const float* __restrict__ whh, const float* __restrict__ wih,
    const float* __restrict__ ow1, const float* __restrict__ rw1,
    const float* __restrict__ ow2, const float* __restrict__ rw2,
    const float* __restrict__ ob0, const float* __restrict__ rb0,
    const float* __restrict__ bhh,
    unsigned short* __restrict__ Ws1, unsigned short* __restrict__ Wih,
    unsigned short* __restrict__ W1o, unsigned short* __restrict__ W1r,
    unsigned short* __restrict__ W2o, unsigned short* __restrict__ w2r,
    float* __restrict__ bias_s1)
{
    const int i0 = blockIdx.x * 256 + threadIdx.x;
    const int stride = gridDim.x * 256;
    for (int i = i0; i < 4096 * 1024; i += stride) {
        int row = i >> 10;
        float v = (row < 512) ? ow0[i]
                : (row < 1024) ? rw0[i - 512 * 1024]
                               : whh[i - 1024 * 1024];
        Ws1[i] = (unsigned short)f2bf(v);
    }
    for (int i = i0; i < GDIM * KIH; i += stride) Wih[i] = (unsigned short)f2bf(wih[i]);
    for (int i = i0; i < FEAT * FEAT; i += stride) {
        W1o[i] = (unsigned short)f2bf(ow1[i]);
        W1r[i] = (unsigned short)f2bf(rw1[i]);
    }
    for (int i = i0; i < OBS_DIM * FEAT; i += stride) W2o[i] = (unsigned short)f2bf(ow2[i]);
    for (int i = i0; i < FEAT; i += stride) w2r[i] = (unsigned short)f2bf(rw2[i]);
    for (int i = i0; i < 4096; i += stride)
        bias_s1[i] = (i < 512) ? ob0[i] : (i < 1024) ? rb0[i - 512] : bhh[i - 1024];
}

__global__ void k_init(const float* __restrict__ obs,
                       unsigned short* __restrict__ Xbuf1,
                       float* __restrict__ accum,
                       int* __restrict__ bar)
{
    int i = blockIdx.x * 256 + threadIdx.x;
    if (i < BATCH * KIH) {
        int row = i / KIH, col = i - row * KIH;
        Xbuf1[i] = (col < OBS_DIM) ? (unsigned short)f2bf(obs[row * OBS_DIM + col])
                                   : (unsigned short)0;
    }
    if (i < 2)    accum[i] = 0.f;
    if (i < 8192) bar[i] = 0;
}

// ---------------------------------------------------------------------------
extern "C" void kernel_launch(void* const* d_in, const int* in_sizes, int n_in,
                              void* d_out, int out_size, void* d_ws, size_t ws_size,
                              hipStream_t stream)
{
    const float* obs      = (const float*)d_in[0];
    const float* action   = (const float*)d_in[1];
    const float* reward   = (const float*)d_in[2];
    const float* gru_w_ih = (const float*)d_in[3];
    const float* gru_w_hh = (const float*)d_in[4];
    const float* gru_b_ih = (const float*)d_in[5];
    const float* gru_b_hh = (const float*)d_in[6];
    const float* obs_w0   = (const float*)d_in[7];
    const float* obs_b0   = (const float*)d_in[8];
    const float* obs_w1   = (const float*)d_in[9];
    const float* obs_b1   = (const float*)d_in[10];
    const float* obs_w2   = (const float*)d_in[11];
    const float* obs_b2   = (const float*)d_in[12];
    const float* rew_w0   = (const float*)d_in[13];
    const float* rew_b0   = (const float*)d_in[14];
    const float* rew_w1   = (const float*)d_in[15];
    const float* rew_b1   = (const float*)d_in[16];
    const float* rew_w2   = (const float*)d_in[17];
    const float* rew_b2   = (const float*)d_in[18];

    char* ws = (char*)d_ws;
    auto alloc = [&](size_t bytes) -> char* {
        char* pr = ws;
        ws += (bytes + 255) & ~(size_t)255;
        return pr;
    };
    unsigned short* Ws1  = (unsigned short*)alloc((size_t)4096 * 1024 * 2);
    unsigned short* Wih  = (unsigned short*)alloc((size_t)GDIM * KIH * 2);
    unsigned short* W1o  = (unsigned short*)alloc((size_t)FEAT * FEAT * 2);
    unsigned short* W1r  = (unsigned short*)alloc((size_t)FEAT * FEAT * 2);
    unsigned short* W2o  = (unsigned short*)alloc((size_t)OBS_DIM * FEAT * 2);
    unsigned short* w2r  = (unsigned short*)alloc((size_t)FEAT * 2);
    float* bias_s1       = (float*)alloc((size_t)4096 * 4);
    unsigned short* Z1a  = (unsigned short*)alloc((size_t)BATCH * HID * 2);
    unsigned short* Z1b  = (unsigned short*)alloc((size_t)BATCH * HID * 2);
    unsigned short* Z2a  = (unsigned short*)alloc((size_t)BATCH * HID * 2);
    unsigned short* Z2b  = (unsigned short*)alloc((size_t)BATCH * HID * 2);
    unsigned short* GHa  = (unsigned short*)alloc((size_t)BATCH * GDIM * 2);
    unsigned short* GHbB = (unsigned short*)alloc((size_t)BATCH * GDIM * 2);
    unsigned short* Xba  = (unsigned short*)alloc((size_t)BATCH * KIH * 2);
    unsigned short* Xbb  = (unsigned short*)alloc((size_t)BATCH * KIH * 2);
    float* ha            = (float*)alloc((size_t)BATCH * HID * 4);
    float* hb            = (float*)alloc((size_t)BATCH * HID * 4);
    unsigned short* hfa  = (unsigned short*)alloc((size_t)BATCH * HID * 2);
    unsigned short* hfb  = (unsigned short*)alloc((size_t)BATCH * HID * 2);
    float* accum         = (float*)alloc(256);
    int*   bar           = (int*)alloc(32768);

    k_convert<<<dim3(1024), dim3(256), 0, stream>>>(
        obs_w0, rew_w0, gru_w_hh, gru_w_ih, obs_w1, rew_w1, obs_w2, rew_w2,
        obs_b0, rew_b0, gru_b_hh, Ws1, Wih, W1o, W1r, W2o, w2r, bias_s1);

    k_init<<<dim3((BATCH * KIH + 255) / 256), dim3(256), 0, stream>>>(obs, Xbb, accum, bar);

    P hp;
    hp.obs = obs; hp.action = action; hp.reward = reward;
    hp.b_ih = gru_b_ih; hp.b_hh = gru_b_hh;
    hp.b1o = obs_b1; hp.b1r = rew_b1; hp.b2o = obs_b2; hp.b2r = rew_b2;
    hp.Ws1 = Ws1; hp.Wih = Wih; hp.W1o = W1o; hp.W1r = W1r;
    hp.W2o = W2o; hp.w2r = w2r; hp.bias_s1 = bias_s1;
    hp.Z1[0] = Z1a; hp.Z1[1] = Z1b;
    hp.Z2[0] = Z2a; hp.Z2[1] = Z2b;
    hp.Xbuf[0] = Xba; hp.Xbuf[1] = Xbb;
    hp.hbf[0] = hfa; hp.hbf[1] = hfb;
    hp.GHb[0] = GHa; hp.GHb[1] = GHbB;
    hp.h[0] = ha; hp.h[1] = hb;
    hp.accum = accum; hp.out = (float*)d_out;
    hp.bar = bar;

    k_persist<<<dim3(NBLK), dim3(256), 0, stream>>>(hp);
}